// Round 5
// baseline (2935.482 us; speedup 1.0000x reference)
//
#include <hip/hip_runtime.h>

typedef unsigned short u16;
typedef unsigned int u32;
typedef __bf16 bf16x8 __attribute__((ext_vector_type(8)));
typedef float f32x4 __attribute__((ext_vector_type(4)));

// ---- ws layout (bytes) ----
#define OFF_XPROJ 0ull                  // 2*256*64*2048 bf16 = 134217728
#define OFF_HBUF  134217728ull          // 2 bufs * 2 dir * 64 * 512 bf16 = 262144
#define OFF_XBF   134479872ull          // 64*256*512 bf16 = 16777216
#define OFF_WXBF  151257088ull          // 4096*512 bf16 = 4194304
#define OFF_BIAS  155451392ull          // 4096 bf16 = 8192
#define OFF_FLAGS 155459584ull          // 2 dir * 32 flags * 64B = 4096

struct WPtrs { const float* p[8]; };

__device__ __forceinline__ u16 f2bf(float f) {
    __bf16 h = (__bf16)f;
    return __builtin_bit_cast(u16, h);
}
__device__ __forceinline__ float bf2f(u16 u) {
    __bf16 h = __builtin_bit_cast(__bf16, u);
    return (float)h;
}
__device__ __forceinline__ u32 pack2(float a, float b) {
    return (u32)f2bf(a) | ((u32)f2bf(b) << 16);
}
__device__ __forceinline__ float sigf(float x) {
    return 1.0f / (1.0f + __expf(-x));
}

// ---------- pack x fp32 -> bf16 ----------
__global__ void __launch_bounds__(256) pack_x(const float* __restrict__ x, u16* __restrict__ xbf) {
    int idx = blockIdx.x * 256 + threadIdx.x;
    int e = idx * 4;
    float4 v = *(const float4*)(x + e);
    xbf[e+0] = f2bf(v.x); xbf[e+1] = f2bf(v.y);
    xbf[e+2] = f2bf(v.z); xbf[e+3] = f2bf(v.w);
}

// ---------- pack Wx (W[:, :512]) fp32 -> bf16, layout [n=(d,g,j)][k] ----------
__global__ void __launch_bounds__(256) pack_w(WPtrs wp, u16* __restrict__ wxbf) {
    int idx = blockIdx.x * 256 + threadIdx.x;
    int e = idx * 4;
    int n = e >> 9;
    int k = e & 511;
    int j = n & 511, g = (n >> 9) & 3, d = n >> 11;
    const float* W = wp.p[d*4 + g];
    float4 v = *(const float4*)(W + j*1024 + k);
    wxbf[n*512 + k + 0] = f2bf(v.x); wxbf[n*512 + k + 1] = f2bf(v.y);
    wxbf[n*512 + k + 2] = f2bf(v.z); wxbf[n*512 + k + 3] = f2bf(v.w);
}

// ---------- pack bias (bf16), zero barrier flags ----------
__global__ void __launch_bounds__(256) pack_bias(WPtrs bp, u16* __restrict__ biasws, unsigned* flagws) {
    int idx = blockIdx.x * 256 + threadIdx.x;   // 0..4095
    int j = idx & 511, g = (idx >> 9) & 3, d = idx >> 11;
    biasws[idx] = f2bf(bp.p[d*4 + g][j]);
    if (idx < 1024) flagws[idx] = 0u;           // 2*32*16 flag dwords
}

// ---------- xproj GEMM: xproj[d][t][b][g*512+j] = x[b][t]·Wx^T + bias (bf16 out) ----------
__global__ void __launch_bounds__(256) gemm_xproj(const u16* __restrict__ xbf,
                                                  const u16* __restrict__ wxbf,
                                                  const u16* __restrict__ biasws,
                                                  u16* __restrict__ xproj) {
    __shared__ u16 A[64 * 264];
    int tid = threadIdx.x, w = tid >> 6, lane = tid & 63, q = lane >> 4, ln = lane & 15;
    int mb = blockIdx.x >> 6, nb = blockIdx.x & 63;
    int n = nb*64 + w*16 + ln;

    bf16x8 bfr[16];
    #pragma unroll
    for (int kk = 0; kk < 16; ++kk)
        bfr[kk] = *(const bf16x8*)(wxbf + n*512 + kk*32 + q*8);
    float bias = bf2f(biasws[n]);

    f32x4 acc[4] = {{0.f,0.f,0.f,0.f},{0.f,0.f,0.f,0.f},{0.f,0.f,0.f,0.f},{0.f,0.f,0.f,0.f}};
    const u16* Abase = xbf + (size_t)mb * 64 * 512;

    for (int half = 0; half < 2; ++half) {
        for (int it = 0; it < 8; ++it) {
            int idx = tid + it*256;
            int r = idx >> 5, c = idx & 31;
            *(uint4*)&A[r*264 + c*8] = *(const uint4*)(Abase + r*512 + half*256 + c*8);
        }
        __syncthreads();
        #pragma unroll
        for (int kk = 0; kk < 8; ++kk) {
            #pragma unroll
            for (int mt = 0; mt < 4; ++mt) {
                bf16x8 af = *(const bf16x8*)&A[(mt*16 + ln)*264 + kk*32 + q*8];
                acc[mt] = __builtin_amdgcn_mfma_f32_16x16x32_bf16(af, bfr[half*8 + kk], acc[mt], 0, 0, 0);
            }
        }
        __syncthreads();
    }

    int dd = n >> 11, gg = (n >> 9) & 3, jj = n & 511;
    #pragma unroll
    for (int mt = 0; mt < 4; ++mt) {
        #pragma unroll
        for (int r2 = 0; r2 < 4; ++r2) {
            int m = mb*64 + mt*16 + q*4 + r2;
            int t = m & 255, b = m >> 8;
            float v = acc[mt][r2] + bias;
            xproj[(size_t)((dd*256 + t)*64 + b) * 2048 + gg*512 + jj] = f2bf(v);
        }
    }
}

// ---------- leaderless per-direction barrier (no wbl2 anywhere) ----------
__device__ __forceinline__ void bar_store(unsigned* flags, int cb, int tid, unsigned epoch) {
    if (tid == 0)
        __hip_atomic_store(&flags[cb*16], epoch, __ATOMIC_RELAXED, __HIP_MEMORY_SCOPE_AGENT);
}
__device__ __forceinline__ void bar_wait(unsigned* flags, int tid, unsigned epoch) {
    if (tid < 32) {
        while (__hip_atomic_load(&flags[tid*16], __ATOMIC_RELAXED, __HIP_MEMORY_SCOPE_AGENT) < epoch)
            __builtin_amdgcn_s_sleep(1);
    }
    if (tid == 0)   // acquire: buffer_inv (cheap), no writeback
        (void)__hip_atomic_load(&flags[0], __ATOMIC_ACQUIRE, __HIP_MEMORY_SCOPE_AGENT);
    __syncthreads();
}

// ---------- recurrent kernel: 64 blocks = 2 dirs x 32 col-slices ----------
__global__ void __launch_bounds__(256) bilstm_rec(const u16* __restrict__ xproj,
                                                  u16* __restrict__ hbuf,
                                                  float* __restrict__ out,
                                                  WPtrs wp, unsigned* flagbase) {
    __shared__ float pre[4 * 64 * 17];   // raw MFMA gate sums (17408 B)
    __shared__ float cst[1024];          // cell state (4096 B)
    __shared__ u16 xpbuf[4 * 64 * 16];   // prefetched xproj tile (8192 B)

    int tid = threadIdx.x, w = tid >> 6, lane = tid & 63, q = lane >> 4, ln = lane & 15;
    int d = blockIdx.x >> 5, cb = blockIdx.x & 31, j0 = cb * 16;
    unsigned* flags = flagbase + d*512;
    u32* hb32 = (u32*)hbuf;

    // Wh fragments: persistent in registers. Wave w = gate w; lane holds row j0+ln.
    const float* Wg = wp.p[d*4 + w];
    bf16x8 bfr[16];
    #pragma unroll
    for (int kk = 0; kk < 16; ++kk) {
        const float* src = Wg + (j0 + ln)*1024 + 512 + kk*32 + q*8;
        float4 v0 = *(const float4*)src;
        float4 v1 = *(const float4*)(src + 4);
        bf16x8 t;
        t[0]=(__bf16)v0.x; t[1]=(__bf16)v0.y; t[2]=(__bf16)v0.z; t[3]=(__bf16)v0.w;
        t[4]=(__bf16)v1.x; t[5]=(__bf16)v1.y; t[6]=(__bf16)v1.z; t[7]=(__bf16)v1.w;
        bfr[kk] = t;
    }

    // init: zero cell state; zero own h slice of buf 0 via L2-bypassing stores
    #pragma unroll
    for (int k = 0; k < 4; ++k) cst[tid*4 + k] = 0.f;
    #pragma unroll
    for (int i = 0; i < 2; ++i) {
        int dw = tid*2 + i;              // 0..511 (own slice = 512 dwords)
        int b = dw >> 3, hcw = dw & 7;
        __hip_atomic_store(&hb32[(d*32768 + b*512 + j0)/2 + hcw], 0u,
                           __ATOMIC_RELAXED, __HIP_MEMORY_SCOPE_AGENT);
    }
    // prefetch xproj tile for s=0
    {
        int t0 = d ? 255 : 0;
        const u16* xp_t = xproj + (size_t)((d*256 + t0)*64)*2048 + j0;
        #pragma unroll
        for (int i = 0; i < 2; ++i) {
            int c = tid*2 + i;
            int g = c >> 7, b = (c >> 1) & 63, h8 = c & 1;
            *(uint4*)&xpbuf[c*8] = *(const uint4*)(xp_t + (size_t)b*2048 + g*512 + h8*8);
        }
    }
    __syncthreads();                     // drain h-zero stores
    bar_store(flags, cb, tid, 1u);
    bar_wait(flags, tid, 1u);

    for (int s = 0; s < 256; ++s) {
        int t_ = d ? (255 - s) : s;
        const u16* hsrc = hbuf + ((s & 1)*2 + d) * 32768;
        f32x4 acc[4] = {{0.f,0.f,0.f,0.f},{0.f,0.f,0.f,0.f},{0.f,0.f,0.f,0.f},{0.f,0.f,0.f,0.f}};

        // MFMA: A-fragments gathered straight from global (no LDS staging)
        #pragma unroll
        for (int ks = 0; ks < 16; ++ks) {
            const u16* kbase = hsrc + ks*32 + q*8 + ln*512;
            bf16x8 a0 = *(const bf16x8*)(kbase);
            bf16x8 a1 = *(const bf16x8*)(kbase + 16*512);
            bf16x8 a2 = *(const bf16x8*)(kbase + 32*512);
            bf16x8 a3 = *(const bf16x8*)(kbase + 48*512);
            acc[0] = __builtin_amdgcn_mfma_f32_16x16x32_bf16(a0, bfr[ks], acc[0], 0, 0, 0);
            acc[1] = __builtin_amdgcn_mfma_f32_16x16x32_bf16(a1, bfr[ks], acc[1], 0, 0, 0);
            acc[2] = __builtin_amdgcn_mfma_f32_16x16x32_bf16(a2, bfr[ks], acc[2], 0, 0, 0);
            acc[3] = __builtin_amdgcn_mfma_f32_16x16x32_bf16(a3, bfr[ks], acc[3], 0, 0, 0);
        }

        // stash raw gate sums for the cross-wave cell phase
        #pragma unroll
        for (int mt = 0; mt < 4; ++mt) {
            #pragma unroll
            for (int r2 = 0; r2 < 4; ++r2)
                pre[w*1088 + (mt*16 + q*4 + r2)*17 + ln] = acc[mt][r2];
        }
        __syncthreads();

        // cell elementwise: thread owns (b = tid>>2, hc0 = (tid&3)*4 .. +3)
        int b = tid >> 2, hc0 = (tid & 3) * 4, p0 = tid * 4;
        int nb_off = (((s + 1) & 1)*2 + d) * 32768;
        float h4[4];
        #pragma unroll
        for (int k = 0; k < 4; ++k) {
            int hc = hc0 + k, p = p0 + k;
            float fpre = pre[0*1088 + b*17 + hc] + bf2f(xpbuf[0*1024 + p]);
            float ipre = pre[1*1088 + b*17 + hc] + bf2f(xpbuf[1*1024 + p]);
            float opre = pre[2*1088 + b*17 + hc] + bf2f(xpbuf[2*1024 + p]);
            float gpre = pre[3*1088 + b*17 + hc] + bf2f(xpbuf[3*1024 + p]);
            float fg = sigf(fpre), ig = sigf(ipre), og = sigf(opre);
            float gg = tanhf(gpre);
            float c = fg * cst[p] + ig * gg;
            cst[p] = c;
            h4[k] = og * tanhf(c);
        }
        // publish h: L2-bypassing relaxed agent stores (dword-packed)
        int dwbase = (nb_off + b*512 + j0 + hc0) >> 1;
        __hip_atomic_store(&hb32[dwbase],     pack2(h4[0], h4[1]), __ATOMIC_RELAXED, __HIP_MEMORY_SCOPE_AGENT);
        __hip_atomic_store(&hb32[dwbase + 1], pack2(h4[2], h4[3]), __ATOMIC_RELAXED, __HIP_MEMORY_SCOPE_AGENT);

        __syncthreads();                 // drains h stores (vmcnt0) + xpbuf reads done
        bar_store(flags, cb, tid, (unsigned)(s + 2));

        // out store — not part of the protocol; drains during next step's compute
        f32x4 o4 = { h4[0], h4[1], h4[2], h4[3] };
        __builtin_nontemporal_store(o4, (f32x4*)&out[(size_t)(t_*64 + b)*1024 + d*512 + j0 + hc0]);

        // prefetch next xproj tile into registers (hidden behind the poll)
        uint4 r0, r1;
        bool havepf = (s + 1 < 256);
        int c0 = tid*2, c1 = tid*2 + 1;
        if (havepf) {
            int tn = d ? (254 - s) : (s + 1);
            const u16* xp_t = xproj + (size_t)((d*256 + tn)*64)*2048 + j0;
            int g0 = c0 >> 7, b0 = (c0 >> 1) & 63, h80 = c0 & 1;
            int g1 = c1 >> 7, b1 = (c1 >> 1) & 63, h81 = c1 & 1;
            r0 = *(const uint4*)(xp_t + (size_t)b0*2048 + g0*512 + h80*8);
            r1 = *(const uint4*)(xp_t + (size_t)b1*2048 + g1*512 + h81*8);
        }

        bar_wait(flags, tid, (unsigned)(s + 2));

        if (havepf) {
            *(uint4*)&xpbuf[c0*8] = r0;
            *(uint4*)&xpbuf[c1*8] = r1;
        }
    }
}

extern "C" void kernel_launch(void* const* d_in, const int* in_sizes, int n_in,
                              void* d_out, int out_size, void* d_ws, size_t ws_size,
                              hipStream_t stream) {
    const float* x = (const float*)d_in[0];
    WPtrs wp, bp;
    for (int d = 0; d < 2; ++d) {
        for (int g = 0; g < 4; ++g) {
            wp.p[d*4 + g] = (const float*)d_in[1 + d*8 + g*2];
            bp.p[d*4 + g] = (const float*)d_in[2 + d*8 + g*2];
        }
    }
    char* ws = (char*)d_ws;
    u16* xproj    = (u16*)(ws + OFF_XPROJ);
    u16* hbuf     = (u16*)(ws + OFF_HBUF);
    u16* xbf      = (u16*)(ws + OFF_XBF);
    u16* wxbf     = (u16*)(ws + OFF_WXBF);
    u16* biasw    = (u16*)(ws + OFF_BIAS);
    unsigned* flg = (unsigned*)(ws + OFF_FLAGS);
    float* out = (float*)d_out;

    hipLaunchKernelGGL(pack_x, dim3(8192), dim3(256), 0, stream, x, xbf);
    hipLaunchKernelGGL(pack_w, dim3(2048), dim3(256), 0, stream, wp, wxbf);
    hipLaunchKernelGGL(pack_bias, dim3(16), dim3(256), 0, stream, bp, biasw, flg);
    hipLaunchKernelGGL(gemm_xproj, dim3(16384), dim3(256), 0, stream,
                       (const u16*)xbf, (const u16*)wxbf, (const u16*)biasw, xproj);

    const u16* xproj_c = xproj;
    void* args[] = { (void*)&xproj_c, (void*)&hbuf, (void*)&out, (void*)&wp, (void*)&flg };
    (void)hipLaunchCooperativeKernel((const void*)bilstm_rec, dim3(64), dim3(256), args, 0, stream);
}

// Round 6
// 1654.127 us; speedup vs baseline: 1.7746x; 1.7746x over previous
//
#include <hip/hip_runtime.h>

typedef unsigned short u16;
typedef unsigned int u32;
typedef __bf16 bf16x8 __attribute__((ext_vector_type(8)));
typedef float f32x4 __attribute__((ext_vector_type(4)));

// ---- ws layout (bytes) ----
#define OFF_XPROJ 0ull                  // 2*256*64*2048 bf16 = 134217728
#define OFF_HBUF  134217728ull          // 2 bufs * 2 dir * 64 * 512 bf16 = 262144
#define OFF_XBF   134479872ull          // 64*256*512 bf16 = 16777216
#define OFF_WXBF  151257088ull          // 4096*512 bf16 = 4194304
#define OFF_BIAS  155451392ull          // 4096 bf16 = 8192
#define OFF_FLAGS 155459584ull          // 2 dir * 32 flags * 64B = 4096

struct WPtrs { const float* p[8]; };

__device__ __forceinline__ u16 f2bf(float f) {
    __bf16 h = (__bf16)f;
    return __builtin_bit_cast(u16, h);
}
__device__ __forceinline__ float bf2f(u16 u) {
    __bf16 h = __builtin_bit_cast(__bf16, u);
    return (float)h;
}
__device__ __forceinline__ u32 pack2(float a, float b) {
    return (u32)f2bf(a) | ((u32)f2bf(b) << 16);
}
__device__ __forceinline__ float sigf(float x) {
    return 1.0f / (1.0f + __expf(-x));
}

// ---------- pack x fp32 -> bf16 ----------
__global__ void __launch_bounds__(256) pack_x(const float* __restrict__ x, u16* __restrict__ xbf) {
    int idx = blockIdx.x * 256 + threadIdx.x;
    int e = idx * 4;
    float4 v = *(const float4*)(x + e);
    xbf[e+0] = f2bf(v.x); xbf[e+1] = f2bf(v.y);
    xbf[e+2] = f2bf(v.z); xbf[e+3] = f2bf(v.w);
}

// ---------- pack Wx (W[:, :512]) fp32 -> bf16, layout [n=(d,g,j)][k] ----------
__global__ void __launch_bounds__(256) pack_w(WPtrs wp, u16* __restrict__ wxbf) {
    int idx = blockIdx.x * 256 + threadIdx.x;
    int e = idx * 4;
    int n = e >> 9;
    int k = e & 511;
    int j = n & 511, g = (n >> 9) & 3, d = n >> 11;
    const float* W = wp.p[d*4 + g];
    float4 v = *(const float4*)(W + j*1024 + k);
    wxbf[n*512 + k + 0] = f2bf(v.x); wxbf[n*512 + k + 1] = f2bf(v.y);
    wxbf[n*512 + k + 2] = f2bf(v.z); wxbf[n*512 + k + 3] = f2bf(v.w);
}

// ---------- pack bias (bf16), zero barrier flags ----------
__global__ void __launch_bounds__(256) pack_bias(WPtrs bp, u16* __restrict__ biasws, unsigned* flagws) {
    int idx = blockIdx.x * 256 + threadIdx.x;   // 0..4095
    int j = idx & 511, g = (idx >> 9) & 3, d = idx >> 11;
    biasws[idx] = f2bf(bp.p[d*4 + g][j]);
    if (idx < 1024) flagws[idx] = 0u;           // 2*32*16 flag dwords
}

// ---------- xproj GEMM: xproj[d][t][b][g*512+j] = x[b][t]·Wx^T + bias (bf16 out) ----------
__global__ void __launch_bounds__(256) gemm_xproj(const u16* __restrict__ xbf,
                                                  const u16* __restrict__ wxbf,
                                                  const u16* __restrict__ biasws,
                                                  u16* __restrict__ xproj) {
    __shared__ u16 A[64 * 264];
    int tid = threadIdx.x, w = tid >> 6, lane = tid & 63, q = lane >> 4, ln = lane & 15;
    int mb = blockIdx.x >> 6, nb = blockIdx.x & 63;
    int n = nb*64 + w*16 + ln;

    bf16x8 bfr[16];
    #pragma unroll
    for (int kk = 0; kk < 16; ++kk)
        bfr[kk] = *(const bf16x8*)(wxbf + n*512 + kk*32 + q*8);
    float bias = bf2f(biasws[n]);

    f32x4 acc[4] = {{0.f,0.f,0.f,0.f},{0.f,0.f,0.f,0.f},{0.f,0.f,0.f,0.f},{0.f,0.f,0.f,0.f}};
    const u16* Abase = xbf + (size_t)mb * 64 * 512;

    for (int half = 0; half < 2; ++half) {
        for (int it = 0; it < 8; ++it) {
            int idx = tid + it*256;
            int r = idx >> 5, c = idx & 31;
            *(uint4*)&A[r*264 + c*8] = *(const uint4*)(Abase + r*512 + half*256 + c*8);
        }
        __syncthreads();
        #pragma unroll
        for (int kk = 0; kk < 8; ++kk) {
            #pragma unroll
            for (int mt = 0; mt < 4; ++mt) {
                bf16x8 af = *(const bf16x8*)&A[(mt*16 + ln)*264 + kk*32 + q*8];
                acc[mt] = __builtin_amdgcn_mfma_f32_16x16x32_bf16(af, bfr[half*8 + kk], acc[mt], 0, 0, 0);
            }
        }
        __syncthreads();
    }

    int dd = n >> 11, gg = (n >> 9) & 3, jj = n & 511;
    #pragma unroll
    for (int mt = 0; mt < 4; ++mt) {
        #pragma unroll
        for (int r2 = 0; r2 < 4; ++r2) {
            int m = mb*64 + mt*16 + q*4 + r2;
            int t = m & 255, b = m >> 8;
            float v = acc[mt][r2] + bias;
            xproj[(size_t)((dd*256 + t)*64 + b) * 2048 + gg*512 + jj] = f2bf(v);
        }
    }
}

// ---------- leaderless per-direction barrier (no wbl2 anywhere) ----------
__device__ __forceinline__ void bar_store(unsigned* flags, int cb, int tid, unsigned epoch) {
    if (tid == 0)
        __hip_atomic_store(&flags[cb*16], epoch, __ATOMIC_RELAXED, __HIP_MEMORY_SCOPE_AGENT);
}
__device__ __forceinline__ void bar_wait(unsigned* flags, int tid, unsigned epoch) {
    if (tid < 32) {
        while (__hip_atomic_load(&flags[tid*16], __ATOMIC_RELAXED, __HIP_MEMORY_SCOPE_AGENT) < epoch)
            __builtin_amdgcn_s_sleep(1);
    }
    if (tid == 0)   // acquire: buffer_inv (cheap), no writeback
        (void)__hip_atomic_load(&flags[0], __ATOMIC_ACQUIRE, __HIP_MEMORY_SCOPE_AGENT);
    __syncthreads();
}

// ---------- recurrent kernel: 64 blocks = 2 dirs x 32 col-slices ----------
__global__ void __launch_bounds__(256) bilstm_rec(const u16* __restrict__ xproj,
                                                  u16* __restrict__ hbuf,
                                                  float* __restrict__ out,
                                                  WPtrs wp, unsigned* flagbase) {
    __shared__ u16 A[64 * 264];          // h half-tile staging (33792 B)
    __shared__ float pre[4 * 64 * 17];   // raw MFMA gate sums (17408 B)
    __shared__ float cst[1024];          // cell state (4096 B)
    __shared__ u16 xpbuf[4 * 64 * 16];   // prefetched xproj tile (8192 B)

    int tid = threadIdx.x, w = tid >> 6, lane = tid & 63, q = lane >> 4, ln = lane & 15;
    int d = blockIdx.x >> 5, cb = blockIdx.x & 31, j0 = cb * 16;
    unsigned* flags = flagbase + d*512;
    u32* hb32 = (u32*)hbuf;

    // Wh fragments: persistent in registers. Wave w = gate w; lane holds row j0+ln.
    const float* Wg = wp.p[d*4 + w];
    bf16x8 bfr[16];
    #pragma unroll
    for (int kk = 0; kk < 16; ++kk) {
        const float* src = Wg + (j0 + ln)*1024 + 512 + kk*32 + q*8;
        float4 v0 = *(const float4*)src;
        float4 v1 = *(const float4*)(src + 4);
        bf16x8 t;
        t[0]=(__bf16)v0.x; t[1]=(__bf16)v0.y; t[2]=(__bf16)v0.z; t[3]=(__bf16)v0.w;
        t[4]=(__bf16)v1.x; t[5]=(__bf16)v1.y; t[6]=(__bf16)v1.z; t[7]=(__bf16)v1.w;
        bfr[kk] = t;
    }

    // init: zero cell state; zero own h slice of buf 0 via agent stores
    #pragma unroll
    for (int k = 0; k < 4; ++k) cst[tid*4 + k] = 0.f;
    #pragma unroll
    for (int i = 0; i < 2; ++i) {
        int dw = tid*2 + i;              // 0..511 (own slice = 512 dwords)
        int b = dw >> 3, hcw = dw & 7;
        __hip_atomic_store(&hb32[(d*32768 + b*512 + j0)/2 + hcw], 0u,
                           __ATOMIC_RELAXED, __HIP_MEMORY_SCOPE_AGENT);
    }
    // prefetch xproj tile for s=0
    {
        int t0 = d ? 255 : 0;
        const u16* xp_t = xproj + (size_t)((d*256 + t0)*64)*2048 + j0;
        #pragma unroll
        for (int i = 0; i < 2; ++i) {
            int c = tid*2 + i;
            int g = c >> 7, b = (c >> 1) & 63, h8 = c & 1;
            *(uint4*)&xpbuf[c*8] = *(const uint4*)(xp_t + (size_t)b*2048 + g*512 + h8*8);
        }
    }
    __syncthreads();                     // drain h-zero stores
    bar_store(flags, cb, tid, 1u);
    bar_wait(flags, tid, 1u);

    for (int s = 0; s < 256; ++s) {
        int t_ = d ? (255 - s) : s;
        const u16* hsrc = hbuf + ((s & 1)*2 + d) * 32768;
        f32x4 acc[4] = {{0.f,0.f,0.f,0.f},{0.f,0.f,0.f,0.f},{0.f,0.f,0.f,0.f},{0.f,0.f,0.f,0.f}};

        // MFMA with coalesced LDS staging of the h tile, two K-halves
        for (int half = 0; half < 2; ++half) {
            #pragma unroll
            for (int it = 0; it < 8; ++it) {
                int idx = tid + it*256;
                int r = idx >> 5, c = idx & 31;
                *(uint4*)&A[r*264 + c*8] = *(const uint4*)(hsrc + r*512 + half*256 + c*8);
            }
            __syncthreads();
            #pragma unroll
            for (int kk = 0; kk < 8; ++kk) {
                #pragma unroll
                for (int mt = 0; mt < 4; ++mt) {
                    bf16x8 af = *(const bf16x8*)&A[(mt*16 + ln)*264 + kk*32 + q*8];
                    acc[mt] = __builtin_amdgcn_mfma_f32_16x16x32_bf16(af, bfr[half*8 + kk], acc[mt], 0, 0, 0);
                }
            }
            __syncthreads();
        }

        // stash raw gate sums for the cross-wave cell phase
        #pragma unroll
        for (int mt = 0; mt < 4; ++mt) {
            #pragma unroll
            for (int r2 = 0; r2 < 4; ++r2)
                pre[w*1088 + (mt*16 + q*4 + r2)*17 + ln] = acc[mt][r2];
        }
        __syncthreads();

        // cell elementwise: thread owns (b = tid>>2, hc0 = (tid&3)*4 .. +3)
        int b = tid >> 2, hc0 = (tid & 3) * 4, p0 = tid * 4;
        int nb_off = (((s + 1) & 1)*2 + d) * 32768;
        float h4[4];
        #pragma unroll
        for (int k = 0; k < 4; ++k) {
            int hc = hc0 + k, p = p0 + k;
            float fpre = pre[0*1088 + b*17 + hc] + bf2f(xpbuf[0*1024 + p]);
            float ipre = pre[1*1088 + b*17 + hc] + bf2f(xpbuf[1*1024 + p]);
            float opre = pre[2*1088 + b*17 + hc] + bf2f(xpbuf[2*1024 + p]);
            float gpre = pre[3*1088 + b*17 + hc] + bf2f(xpbuf[3*1024 + p]);
            float fg = sigf(fpre), ig = sigf(ipre), og = sigf(opre);
            float gg = tanhf(gpre);
            float c = fg * cst[p] + ig * gg;
            cst[p] = c;
            h4[k] = og * tanhf(c);
        }
        // publish h: relaxed agent stores land at the coherence point (no wbl2 needed)
        int dwbase = (nb_off + b*512 + j0 + hc0) >> 1;
        __hip_atomic_store(&hb32[dwbase],     pack2(h4[0], h4[1]), __ATOMIC_RELAXED, __HIP_MEMORY_SCOPE_AGENT);
        __hip_atomic_store(&hb32[dwbase + 1], pack2(h4[2], h4[3]), __ATOMIC_RELAXED, __HIP_MEMORY_SCOPE_AGENT);

        __syncthreads();                 // drains h stores (vmcnt0) + xpbuf reads done
        bar_store(flags, cb, tid, (unsigned)(s + 2));

        // out store — not part of the protocol; drains during next step's compute
        f32x4 o4 = { h4[0], h4[1], h4[2], h4[3] };
        __builtin_nontemporal_store(o4, (f32x4*)&out[(size_t)(t_*64 + b)*1024 + d*512 + j0 + hc0]);

        // prefetch next xproj tile into registers (hidden behind the poll)
        uint4 r0, r1;
        bool havepf = (s + 1 < 256);
        int c0 = tid*2, c1 = tid*2 + 1;
        if (havepf) {
            int tn = d ? (254 - s) : (s + 1);
            const u16* xp_t = xproj + (size_t)((d*256 + tn)*64)*2048 + j0;
            int g0 = c0 >> 7, b0 = (c0 >> 1) & 63, h80 = c0 & 1;
            int g1 = c1 >> 7, b1 = (c1 >> 1) & 63, h81 = c1 & 1;
            r0 = *(const uint4*)(xp_t + (size_t)b0*2048 + g0*512 + h80*8);
            r1 = *(const uint4*)(xp_t + (size_t)b1*2048 + g1*512 + h81*8);
        }

        bar_wait(flags, tid, (unsigned)(s + 2));

        if (havepf) {
            *(uint4*)&xpbuf[c0*8] = r0;
            *(uint4*)&xpbuf[c1*8] = r1;
        }
    }
}

extern "C" void kernel_launch(void* const* d_in, const int* in_sizes, int n_in,
                              void* d_out, int out_size, void* d_ws, size_t ws_size,
                              hipStream_t stream) {
    const float* x = (const float*)d_in[0];
    WPtrs wp, bp;
    for (int d = 0; d < 2; ++d) {
        for (int g = 0; g < 4; ++g) {
            wp.p[d*4 + g] = (const float*)d_in[1 + d*8 + g*2];
            bp.p[d*4 + g] = (const float*)d_in[2 + d*8 + g*2];
        }
    }
    char* ws = (char*)d_ws;
    u16* xproj    = (u16*)(ws + OFF_XPROJ);
    u16* hbuf     = (u16*)(ws + OFF_HBUF);
    u16* xbf      = (u16*)(ws + OFF_XBF);
    u16* wxbf     = (u16*)(ws + OFF_WXBF);
    u16* biasw    = (u16*)(ws + OFF_BIAS);
    unsigned* flg = (unsigned*)(ws + OFF_FLAGS);
    float* out = (float*)d_out;

    hipLaunchKernelGGL(pack_x, dim3(8192), dim3(256), 0, stream, x, xbf);
    hipLaunchKernelGGL(pack_w, dim3(2048), dim3(256), 0, stream, wp, wxbf);
    hipLaunchKernelGGL(pack_bias, dim3(16), dim3(256), 0, stream, bp, biasw, flg);
    hipLaunchKernelGGL(gemm_xproj, dim3(16384), dim3(256), 0, stream,
                       (const u16*)xbf, (const u16*)wxbf, (const u16*)biasw, xproj);

    const u16* xproj_c = xproj;
    void* args[] = { (void*)&xproj_c, (void*)&hbuf, (void*)&out, (void*)&wp, (void*)&flg };
    (void)hipLaunchCooperativeKernel((const void*)bilstm_rec, dim3(64), dim3(256), args, 0, stream);
}